// Round 8
// baseline (109.812 us; speedup 1.0000x reference)
//
#include <hip/hip_runtime.h>
#include <hip/hip_bf16.h>

// B=64, T=256, D=128, H=8, E=128, H*E=1024.
// Algebra (verified R1-R7): with xw[b]=Ws^T x[b], Sw=sum(Ws):
//   Kw[b,he]   = xw[b] @ Wk[:,he] + Sw*bk[he]
//   wqk[b,h,d] = scale * sum_e Wq[d,h*128+e]*Kw[b,h,e]   (bq, bs drop: shift-invariant)
//   beta[b,h,t]= softmax_t( x[b,t] . wqk[b,h] )
//   xb[b,h,d]  = sum_t beta[b,h,t]*x[b,t,d]
//   res[b,he]  = xb[b,h] @ Wv[:,he] + bv[he]             (sum_t beta = 1)
//   out[b,d']  = res[b] @ Wo[:,d'] + bo[d']
//
// R8: grid (64,8) x 256 (block = one (b,head); 512 blocks = 2 blocks/CU so two
// INDEPENDENT phase-chains overlap per CU — R4-R7 had 1 block/CU and lockstep
// barriers, leaving ~900cyc cold-miss latency fully exposed). x[b] is held in
// VGPRs (32 float4, loaded once) — phases D/E need no global reads. Weight
// phases stream 64KB head-slices with 16-deep independent float4 loads.
// BAR() = lgkmcnt-only barrier (no vmcnt drain). 8-producer flag handshake.

#define SCALE 0.08838834764831845f  // 1/sqrt(128)
#define MAGIC 0x13579BDFu
#define BAR() __asm__ volatile("s_waitcnt lgkmcnt(0)\n\ts_barrier" ::: "memory")

__global__ __launch_bounds__(256, 2)
void ta_one(const float* __restrict__ x,  const float* __restrict__ Wq,
            const float* __restrict__ Wk, const float* __restrict__ bk,
            const float* __restrict__ Wv, const float* __restrict__ bv,
            const float* __restrict__ Wsv,
            const float* __restrict__ Wo, const float* __restrict__ bov,
            float* __restrict__ ws, float* __restrict__ out)
{
    __shared__ __align__(16) float buf[8224];   // D: [32 q][257]; A/C/E/G partials
    __shared__ __align__(16) float pB[1024];    // B/F partials [8][128]
    __shared__ __align__(16) float wsS[256];
    __shared__ __align__(16) float xwS[128];
    __shared__ __align__(16) float kwS[128];
    __shared__ __align__(16) float wqkS[128];
    __shared__ __align__(16) float betaS[256];
    __shared__ __align__(16) float xbS[128];
    __shared__ __align__(16) float resS[128];
    __shared__ float smx[4], sms[4];
    __shared__ float swS;

    const int tid = threadIdx.x;
    const int b = blockIdx.x, h = blockIdx.y;
    const int w = tid >> 6, l = tid & 63;
    const int q  = tid & 31, tc = tid >> 5;   // lane-of-32, chunk-of-8
    const int c8 = tid & 7,  r8 = tid >> 3;   // row-dot mapping (C)
    const float* xp0 = x + (size_t)b * 32768;

    // ---------- load x[b] into registers (t = tc*32+j, 16B at 4q) ----------
    float4 rx[32];
    #pragma unroll
    for (int j = 0; j < 32; ++j)
        rx[j] = ((const float4*)(xp0 + (size_t)(tc * 32 + j) * 128))[q];
    const float bkv = bk[h * 128 + (tid & 127)];
    const float bvv = bv[h * 128 + (tid & 127)];
    if (tid < 64) *(float4*)(wsS + 4 * tid) = *(const float4*)(Wsv + 4 * tid);
    BAR();

    // ---------- A: xw[d] = sum_t Ws[t]*x[t,d] ----------
    {
        float4 acc = {0.f, 0.f, 0.f, 0.f};
        #pragma unroll
        for (int j = 0; j < 32; ++j) {
            const float s = wsS[tc * 32 + j];
            acc.x += s * rx[j].x; acc.y += s * rx[j].y;
            acc.z += s * rx[j].z; acc.w += s * rx[j].w;
        }
        *(float4*)(buf + tc * 128 + 4 * q) = acc;
    }
    BAR();
    if (tid < 128) {
        float v = 0.f;
        #pragma unroll
        for (int g = 0; g < 8; ++g) v += buf[g * 128 + tid];
        xwS[tid] = v;
    } else if (tid < 192) {                    // Sw
        float v = wsS[l] + wsS[l + 64] + wsS[l + 128] + wsS[l + 192];
        #pragma unroll
        for (int off = 32; off; off >>= 1) v += __shfl_xor(v, off, 64);
        if (l == 0) swS = v;
    }
    BAR();

    // ---------- B: Kw[e] = xw . Wk[:, h*128+e] + Sw*bk ----------
    {
        float4 acc = {0.f, 0.f, 0.f, 0.f};
        #pragma unroll
        for (int j = 0; j < 16; ++j) {
            const int k = tc * 16 + j;
            const float4 wv = ((const float4*)(Wk + (size_t)k * 1024 + h * 128))[q];
            const float xv = xwS[k];
            acc.x += xv * wv.x; acc.y += xv * wv.y;
            acc.z += xv * wv.z; acc.w += xv * wv.w;
        }
        *(float4*)(pB + tc * 128 + 4 * q) = acc;
    }
    BAR();
    if (tid < 128) {
        float v = swS * bkv;
        #pragma unroll
        for (int g = 0; g < 8; ++g) v += pB[g * 128 + tid];
        kwS[tid] = v;
    }
    BAR();

    // ---------- C: wqk[o] = Wq[o, h*128..] . kw  (row-dot, 8-lane 128B groups) --
    {
        #pragma unroll
        for (int rr = 0; rr < 4; ++rr) {
            const int o = 32 * rr + r8;
            const float* base = Wq + (size_t)o * 1024 + h * 128;
            float a = 0.f;
            #pragma unroll
            for (int m = 0; m < 4; ++m) {
                const int j4 = c8 + 8 * m;
                const float4 wv = *(const float4*)(base + 4 * j4);
                const float4 kv = *(const float4*)(kwS + 4 * j4);
                a += wv.x * kv.x + wv.y * kv.y + wv.z * kv.z + wv.w * kv.w;
            }
            buf[c8 * 257 + o] = a;
        }
    }
    BAR();
    if (tid < 128) {
        float v = 0.f;
        #pragma unroll
        for (int g = 0; g < 8; ++g) v += buf[g * 257 + tid];
        wqkS[tid] = v * SCALE;
    }
    BAR();

    // ---------- D: score[t] = x[t] . wqk  (in-reg x, LDS partial reduce) ------
    {
        const float4 qv = ((const float4*)wqkS)[q];
        #pragma unroll
        for (int j = 0; j < 32; ++j) {
            const float s = rx[j].x * qv.x + rx[j].y * qv.y
                          + rx[j].z * qv.z + rx[j].w * qv.w;
            buf[q * 257 + tc * 32 + j] = s;
        }
    }
    BAR();

    // ---------- softmax over t (thread = t) ----------
    {
        float v = 0.f;
        #pragma unroll
        for (int g = 0; g < 32; ++g) v += buf[g * 257 + tid];
        float m = v;
        #pragma unroll
        for (int off = 32; off; off >>= 1) m = fmaxf(m, __shfl_xor(m, off, 64));
        if (l == 0) smx[w] = m;
        BAR();
        const float M = fmaxf(fmaxf(smx[0], smx[1]), fmaxf(smx[2], smx[3]));
        const float e = __expf(v - M);
        float ssum = e;
        #pragma unroll
        for (int off = 32; off; off >>= 1) ssum += __shfl_xor(ssum, off, 64);
        if (l == 0) sms[w] = ssum;
        BAR();
        betaS[tid] = e / (sms[0] + sms[1] + sms[2] + sms[3]);
    }
    BAR();

    // ---------- E: xb[d] = sum_t beta[t]*x[t,d]  (in-reg x) ----------
    {
        float4 acc = {0.f, 0.f, 0.f, 0.f};
        #pragma unroll
        for (int j = 0; j < 32; ++j) {
            const float bb = betaS[tc * 32 + j];
            acc.x += bb * rx[j].x; acc.y += bb * rx[j].y;
            acc.z += bb * rx[j].z; acc.w += bb * rx[j].w;
        }
        *(float4*)(buf + tc * 128 + 4 * q) = acc;
    }
    BAR();
    if (tid < 128) {
        float v = 0.f;
        #pragma unroll
        for (int g = 0; g < 8; ++g) v += buf[g * 128 + tid];
        xbS[tid] = v;
    }
    BAR();

    // ---------- F: res[e] = xb . Wv[:, h*128+e] + bv ----------
    {
        float4 acc = {0.f, 0.f, 0.f, 0.f};
        #pragma unroll
        for (int j = 0; j < 16; ++j) {
            const int dd = tc * 16 + j;
            const float4 wv = ((const float4*)(Wv + (size_t)dd * 1024 + h * 128))[q];
            const float xv = xbS[dd];
            acc.x += xv * wv.x; acc.y += xv * wv.y;
            acc.z += xv * wv.z; acc.w += xv * wv.w;
        }
        *(float4*)(pB + tc * 128 + 4 * q) = acc;
    }
    BAR();
    if (tid < 128) {
        float v = bvv;
        #pragma unroll
        for (int g = 0; g < 8; ++g) v += pB[g * 128 + tid];
        resS[tid] = v;
    }
    BAR();

    // ---------- G: out-partial[d] = sum_e res[e]*Wo[h*128+e, d] ----------
    {
        float4 acc = {0.f, 0.f, 0.f, 0.f};
        #pragma unroll
        for (int j = 0; j < 16; ++j) {
            const int e = tc * 16 + j;
            const float4 wv = ((const float4*)(Wo + (size_t)(h * 128 + e) * 128))[q];
            const float rv = resS[e];
            acc.x += rv * wv.x; acc.y += rv * wv.y;
            acc.z += rv * wv.z; acc.w += rv * wv.w;
        }
        *(float4*)(buf + tc * 128 + 4 * q) = acc;
    }
    __syncthreads();   // full barrier: global-visibility ordering next

    // ---------- cross-block reduce over h (ws poisoned 0xAA each call) --------
    float* part = ws;                               // [64*8*128]
    unsigned* flags = (unsigned*)(ws + 65536);      // [512]
    if (h < 7) {
        if (tid < 128) {
            float v = 0.f;
            #pragma unroll
            for (int g = 0; g < 8; ++g) v += buf[g * 128 + tid];
            part[(size_t)(b * 8 + h) * 128 + tid] = v;
            __threadfence();
        }
        __syncthreads();
        if (tid == 0) atomicExch(&flags[b * 8 + h], MAGIC);
    } else {
        if (tid == 0) {
            #pragma unroll
            for (int i = 0; i < 7; ++i)
                while (atomicCAS(&flags[b * 8 + i], MAGIC, MAGIC) != MAGIC) {}
        }
        __syncthreads();
        if (tid < 128) {
            float v = bov[tid];
            #pragma unroll
            for (int g = 0; g < 8; ++g) v += buf[g * 128 + tid];
            #pragma unroll
            for (int i = 0; i < 7; ++i)
                v += atomicAdd(&part[(size_t)(b * 8 + i) * 128 + tid], 0.f);
            out[(size_t)b * 128 + tid] = v;
        }
    }
}

extern "C" void kernel_launch(void* const* d_in, const int* in_sizes, int n_in,
                              void* d_out, int out_size, void* d_ws, size_t ws_size,
                              hipStream_t stream) {
    const float* x  = (const float*)d_in[0];
    const float* Wq = (const float*)d_in[1];
    // d_in[2] = bq  — softmax shift-invariant, unused
    const float* Wk = (const float*)d_in[3];
    const float* bk = (const float*)d_in[4];
    const float* Wv = (const float*)d_in[5];
    const float* bv = (const float*)d_in[6];
    const float* Ws = (const float*)d_in[7];
    // d_in[8] = bs  — softmax shift-invariant, unused
    const float* Wo = (const float*)d_in[9];
    const float* bo = (const float*)d_in[10];
    float* out = (float*)d_out;
    float* ws  = (float*)d_ws;

    ta_one<<<dim3(64, 8), dim3(256), 0, stream>>>(x, Wq, Wk, bk, Wv, bv, Ws, Wo, bo, ws, out);
}